// Round 2
// baseline (98.681 us; speedup 1.0000x reference)
//
#include <hip/hip_runtime.h>
#include <stdint.h>
#include <stddef.h>

#define BATCH 256
#define IN_F  4096
#define OUT_F 4096
#define BN    16
#define BK    128
#define NT    (IN_F / BK)     // 32 k-steps
#define TPB   512             // 8 waves

// LDS layout (bytes):
//   raw fp32 tiles: 3 bufs x {mu,lv,eps} x (16 rows x 128 f32) = 3 x 24576
//   bf16 W tiles:   2 bufs x (16 x 128 bf16, XOR-swizzled)     = 2 x 4096
#define RAW_BUF   24576
#define RAW_ARR   8192
#define BF_BASE   73728
#define LDS_TOTAL 81920

typedef __attribute__((ext_vector_type(8))) short    bf16x8;
typedef __attribute__((ext_vector_type(4))) float    f32x4;
typedef __attribute__((ext_vector_type(2))) uint32_t u32x2;
typedef __attribute__((ext_vector_type(4))) uint32_t u32x4;

#define MFMA(a,b,c) __builtin_amdgcn_mfma_f32_16x16x32_bf16((a),(b),(c),0,0,0)
#define HALF_LOG2E 0.7213475204444817f   // exp(0.5*x) == exp2(x*HALF_LOG2E)

__device__ __forceinline__ uint32_t pack2bf(float a, float b) {
  uint32_t ua = __builtin_bit_cast(uint32_t, a);
  uint32_t ub = __builtin_bit_cast(uint32_t, b);
  ua += 0x7FFFu + ((ua >> 16) & 1u);
  ub += 0x7FFFu + ((ub >> 16) & 1u);
  return (ua >> 16) | (ub & 0xFFFF0000u);
}

__device__ __forceinline__ bf16x8 cvt8(const float* p) {
  f32x4 v0 = *(const f32x4*)p;
  f32x4 v1 = *(const f32x4*)(p + 4);
  union { u32x4 u; bf16x8 h; } r;
  r.u[0] = pack2bf(v0[0], v0[1]); r.u[1] = pack2bf(v0[2], v0[3]);
  r.u[2] = pack2bf(v1[0], v1[1]); r.u[3] = pack2bf(v1[2], v1[3]);
  return r.h;
}

// async global->LDS, 16B per lane; dest = wave-uniform base + lane*16 (linear)
__device__ __forceinline__ void gload_lds16(const void* g, void* l) {
  __builtin_amdgcn_global_load_lds(
      (const __attribute__((address_space(1))) uint32_t*)g,
      (__attribute__((address_space(3))) uint32_t*)l, 16, 0, 0);
}

// ---------------------------------------------------------------------------
// Prep: x fp32 -> bf16 in ws (2 MiB: L2-resident per XCD during main GEMM);
// bias = bmu + beps*exp(0.5*blv).
// ---------------------------------------------------------------------------
__global__ __launch_bounds__(256) void prep_kernel(
    const float* __restrict__ x,
    const float* __restrict__ bmu,
    const float* __restrict__ blv,
    const float* __restrict__ beps,
    u32x4* __restrict__ xs4,
    float* __restrict__ bias)
{
  const uint32_t b = blockIdx.x;
  if (b < 512u) {
    const uint32_t c = b * 256u + threadIdx.x;   // chunk of 8 floats
    const float* p = x + (size_t)c * 8u;
    f32x4 v0 = *(const f32x4*)p;
    f32x4 v1 = *(const f32x4*)(p + 4);
    u32x4 o;
    o[0] = pack2bf(v0[0], v0[1]); o[1] = pack2bf(v0[2], v0[3]);
    o[2] = pack2bf(v1[0], v1[1]); o[3] = pack2bf(v1[2], v1[3]);
    xs4[c] = o;
  } else {
    const uint32_t i = (b - 512u) * 256u + threadIdx.x;
    bias[i] = fmaf(beps[i], exp2f(blv[i] * HALF_LOG2E), bmu[i]);
  }
}

// ---------------------------------------------------------------------------
// Fused variational GEMM, m97/m201-style async staging:
//   per iter: issue STAGE(t+2) [3 x global_load_lds/wave, raw fp32 W tiles],
//   vmcnt(6) [= 2 tiles x 3 loads in flight, never 0], s_barrier,
//   CVT (LDS fp32 -> swizzled LDS bf16, shared across waves), lgkmcnt(0),
//   s_barrier, MFMA phase (a-frags on demand from L2-resident bf16 xs).
// Grid 256 WGs (1/CU), BN=16 cols, BM=256 (full batch), 8 waves x 32 rows.
// ---------------------------------------------------------------------------
template<bool USE_XS>
__global__ __launch_bounds__(TPB)
void vgemm(const uint16_t* __restrict__ xs,
           const float*    __restrict__ xf,
           const float*    __restrict__ wmu,
           const float*    __restrict__ wlv,
           const float*    __restrict__ weps,
           const float*    __restrict__ biasp,
           const float*    __restrict__ bmu,
           const float*    __restrict__ blv,
           const float*    __restrict__ beps,
           float*          __restrict__ y)
{
  __shared__ __align__(16) uint8_t lds[LDS_TOTAL];

  const int tid = threadIdx.x;
  const int wv  = tid >> 6;
  const int l   = tid & 63;
  const int n0  = blockIdx.x * BN;

  // --- staging/cvt addressing: slot s == tid; r = s>>5, c = (s&31)*4 floats
  const int    sr   = tid >> 5;                    // tile row 0..15
  const size_t goff = (size_t)(n0 + sr) * IN_F + ((tid & 31) << 2);

  // --- cvt write address in swizzled bf16 tile (4 bf16 = 8 B per thread)
  const int c16w = (tid & 31) >> 1;
  const int bfw  = sr * 256 + ((c16w ^ (sr & 7)) << 4) + ((tid & 1) << 3);

  // --- fragment addressing
  const int br = l & 15;       // B row (output col), also a-frag row offset
  const int kb = l >> 4;       // k-octet 0..3
  const int bfo0 = br * 256 + (((0 * 4 + kb) ^ (br & 7)) << 4);
  const int bfo1 = br * 256 + (((1 * 4 + kb) ^ (br & 7)) << 4);
  const int bfo2 = br * 256 + (((2 * 4 + kb) ^ (br & 7)) << 4);
  const int bfo3 = br * 256 + (((3 * 4 + kb) ^ (br & 7)) << 4);
  const int arow0 = wv * 32 + br;

  f32x4 acc0 = {0.f, 0.f, 0.f, 0.f};
  f32x4 acc1 = {0.f, 0.f, 0.f, 0.f};

  auto STAGE = [&](int t, int buf) {
    const size_t go = goff + (size_t)t * BK;
    uint8_t* base = &lds[0] + buf * RAW_BUF + wv * 1024;
    gload_lds16(wmu  + go, base + 0 * RAW_ARR);
    gload_lds16(wlv  + go, base + 1 * RAW_ARR);
    gload_lds16(weps + go, base + 2 * RAW_ARR);
  };

  auto CVT = [&](int t) {
    const uint8_t* rb = &lds[0] + (t % 3) * RAW_BUF;
    f32x4 m = *(const f32x4*)(rb + 0 * RAW_ARR + tid * 16);
    f32x4 v = *(const f32x4*)(rb + 1 * RAW_ARR + tid * 16);
    f32x4 e = *(const f32x4*)(rb + 2 * RAW_ARR + tid * 16);
    u32x2 o;
    o[0] = pack2bf(fmaf(e[0], exp2f(v[0] * HALF_LOG2E), m[0]),
                   fmaf(e[1], exp2f(v[1] * HALF_LOG2E), m[1]));
    o[1] = pack2bf(fmaf(e[2], exp2f(v[2] * HALF_LOG2E), m[2]),
                   fmaf(e[3], exp2f(v[3] * HALF_LOG2E), m[3]));
    *(u32x2*)(&lds[0] + BF_BASE + (t & 1) * 4096 + bfw) = o;
  };

  auto COMP = [&](int t) {
    const uint8_t* bfb = &lds[0] + BF_BASE + (t & 1) * 4096;
    bf16x8 a00, a01, a02, a03, a10, a11, a12, a13;
    if constexpr (USE_XS) {
      const uint16_t* x0 = xs + (size_t)arow0 * IN_F + t * BK + kb * 8;
      const uint16_t* x1 = x0 + (size_t)16 * IN_F;
      a00 = *(const bf16x8*)(x0);      a01 = *(const bf16x8*)(x0 + 32);
      a02 = *(const bf16x8*)(x0 + 64); a03 = *(const bf16x8*)(x0 + 96);
      a10 = *(const bf16x8*)(x1);      a11 = *(const bf16x8*)(x1 + 32);
      a12 = *(const bf16x8*)(x1 + 64); a13 = *(const bf16x8*)(x1 + 96);
    } else {
      const float* x0 = xf + (size_t)arow0 * IN_F + t * BK + kb * 8;
      const float* x1 = x0 + (size_t)16 * IN_F;
      a00 = cvt8(x0);      a01 = cvt8(x0 + 32);
      a02 = cvt8(x0 + 64); a03 = cvt8(x0 + 96);
      a10 = cvt8(x1);      a11 = cvt8(x1 + 32);
      a12 = cvt8(x1 + 64); a13 = cvt8(x1 + 96);
    }
    bf16x8 b0 = *(const bf16x8*)(bfb + bfo0);
    bf16x8 b1 = *(const bf16x8*)(bfb + bfo1);
    bf16x8 b2 = *(const bf16x8*)(bfb + bfo2);
    bf16x8 b3 = *(const bf16x8*)(bfb + bfo3);
    acc0 = MFMA(a00, b0, acc0); acc1 = MFMA(a10, b0, acc1);
    acc0 = MFMA(a01, b1, acc0); acc1 = MFMA(a11, b1, acc1);
    acc0 = MFMA(a02, b2, acc0); acc1 = MFMA(a12, b2, acc1);
    acc0 = MFMA(a03, b3, acc0); acc1 = MFMA(a13, b3, acc1);
  };

  // ---- prologue: tiles 0,1 in flight
  STAGE(0, 0);
  STAGE(1, 1);

  // ---- main loop: counted vmcnt keeps 2 tiles (6 loads/wave) in flight
  for (int t = 0; t < NT - 2; ++t) {
    STAGE(t + 2, (t + 2) % 3);
    asm volatile("s_waitcnt vmcnt(6)" ::: "memory");   // tile t landed
    __builtin_amdgcn_s_barrier();
    CVT(t);
    asm volatile("s_waitcnt lgkmcnt(0)" ::: "memory"); // cvt writes visible
    __builtin_amdgcn_s_barrier();
    COMP(t);
  }
  { // t = NT-2: only tile NT-1 still in flight
    asm volatile("s_waitcnt vmcnt(3)" ::: "memory");
    __builtin_amdgcn_s_barrier();
    CVT(NT - 2);
    asm volatile("s_waitcnt lgkmcnt(0)" ::: "memory");
    __builtin_amdgcn_s_barrier();
    COMP(NT - 2);
  }
  { // t = NT-1: drain
    asm volatile("s_waitcnt vmcnt(0)" ::: "memory");
    __builtin_amdgcn_s_barrier();
    CVT(NT - 1);
    asm volatile("s_waitcnt lgkmcnt(0)" ::: "memory");
    __builtin_amdgcn_s_barrier();
    COMP(NT - 1);
  }

  // ---- epilogue: C/D frag row=(l>>4)*4+i, col=l&15 (validated in R1)
  const int col = n0 + br;
  float bv;
  if constexpr (USE_XS) {
    bv = biasp[col];
  } else {
    bv = fmaf(beps[col], exp2f(blv[col] * HALF_LOG2E), bmu[col]);
  }
  const int rbase = wv * 32 + kb * 4;
#pragma unroll
  for (int i = 0; i < 4; ++i)
    y[(size_t)(rbase + i) * OUT_F + col] = acc0[i] + bv;
#pragma unroll
  for (int i = 0; i < 4; ++i)
    y[(size_t)(rbase + 16 + i) * OUT_F + col] = acc1[i] + bv;
}

// ---------------------------------------------------------------------------
extern "C" void kernel_launch(void* const* d_in, const int* in_sizes, int n_in,
                              void* d_out, int out_size, void* d_ws, size_t ws_size,
                              hipStream_t stream) {
  const float* x    = (const float*)d_in[0];
  const float* wmu  = (const float*)d_in[1];
  const float* wlv  = (const float*)d_in[2];
  const float* bmu  = (const float*)d_in[3];
  const float* blv  = (const float*)d_in[4];
  const float* beps = (const float*)d_in[5];
  const float* bepsB= (const float*)d_in[6];
  // NOTE input order per setup_inputs(): x, weight_mu, weight_logvar,
  //      bias_mu, bias_logvar, weight_eps, bias_eps
  const float* weps = beps;          // d_in[5] = weight_eps
  const float* b_eps = bepsB;        // d_in[6] = bias_eps
  float* y = (float*)d_out;

  const size_t xs_bytes = (size_t)BATCH * IN_F * 2;       // 2 MiB bf16 x
  const size_t need     = xs_bytes + (size_t)OUT_F * 4;   // + bias

  if (d_ws != nullptr && ws_size >= need) {
    uint16_t* xsp  = (uint16_t*)d_ws;
    float*    bias = (float*)((char*)d_ws + xs_bytes);
    prep_kernel<<<528, 256, 0, stream>>>(x, bmu, blv, b_eps, (u32x4*)d_ws, bias);
    vgemm<true><<<OUT_F / BN, TPB, 0, stream>>>(
        xsp, nullptr, wmu, wlv, weps, bias, nullptr, nullptr, nullptr, y);
  } else {
    vgemm<false><<<OUT_F / BN, TPB, 0, stream>>>(
        nullptr, x, wmu, wlv, weps, nullptr, bmu, blv, b_eps, y);
  }
}

// Round 3
// 83.293 us; speedup vs baseline: 1.1847x; 1.1847x over previous
//
#include <hip/hip_runtime.h>
#include <stdint.h>
#include <stddef.h>

#define BATCH 256
#define IN_F  4096
#define OUT_F 4096
#define BN    16          // output cols per WG
#define BK    64          // k per tile
#define KSPLIT 4
#define TPB   256         // 4 waves

// LDS: raw fp32 tiles 2 bufs x {mu,lv,eps} x (16 x 64 f32) = 2 x 12288
//      bf16 W tile (16 x 64 bf16, XOR-swizzled)            = 2048
#define RAW_BUF   12288
#define RAW_ARR   4096
#define BF_BASE   24576
#define LDS_TOTAL 26624

typedef __attribute__((ext_vector_type(8))) short    bf16x8;
typedef __attribute__((ext_vector_type(4))) float    f32x4;
typedef __attribute__((ext_vector_type(2))) uint32_t u32x2;
typedef __attribute__((ext_vector_type(4))) uint32_t u32x4;

#define MFMA(a,b,c) __builtin_amdgcn_mfma_f32_16x16x32_bf16((a),(b),(c),0,0,0)
#define HALF_LOG2E 0.7213475204444817f   // exp(0.5*x) == exp2(x*HALF_LOG2E)

__device__ __forceinline__ uint32_t pack2bf(float a, float b) {
  uint32_t ua = __builtin_bit_cast(uint32_t, a);
  uint32_t ub = __builtin_bit_cast(uint32_t, b);
  ua += 0x7FFFu + ((ua >> 16) & 1u);
  ub += 0x7FFFu + ((ub >> 16) & 1u);
  return (ua >> 16) | (ub & 0xFFFF0000u);
}

__device__ __forceinline__ bf16x8 cvt8(const float* p) {
  f32x4 v0 = *(const f32x4*)p;
  f32x4 v1 = *(const f32x4*)(p + 4);
  union { u32x4 u; bf16x8 h; } r;
  r.u[0] = pack2bf(v0[0], v0[1]); r.u[1] = pack2bf(v0[2], v0[3]);
  r.u[2] = pack2bf(v1[0], v1[1]); r.u[3] = pack2bf(v1[2], v1[3]);
  return r.h;
}

__device__ __forceinline__ void gload_lds16(const void* g, void* l) {
  __builtin_amdgcn_global_load_lds(
      (const __attribute__((address_space(1))) uint32_t*)g,
      (__attribute__((address_space(3))) uint32_t*)l, 16, 0, 0);
}

// ---------------------------------------------------------------------------
// Prep: x fp32 -> bf16 (L2-resident during GEMM); bias = bmu + beps*exp(.5*blv)
// ---------------------------------------------------------------------------
__global__ __launch_bounds__(256) void prep_kernel(
    const float* __restrict__ x,
    const float* __restrict__ bmu,
    const float* __restrict__ blv,
    const float* __restrict__ beps,
    u32x4* __restrict__ xs4,
    float* __restrict__ bias)
{
  const uint32_t b = blockIdx.x;
  if (b < 512u) {
    const uint32_t c = b * 256u + threadIdx.x;
    const float* p = x + (size_t)c * 8u;
    f32x4 v0 = *(const f32x4*)p;
    f32x4 v1 = *(const f32x4*)(p + 4);
    u32x4 o;
    o[0] = pack2bf(v0[0], v0[1]); o[1] = pack2bf(v0[2], v0[3]);
    o[2] = pack2bf(v1[0], v1[1]); o[3] = pack2bf(v1[2], v1[3]);
    xs4[c] = o;
  } else {
    const uint32_t i = (b - 512u) * 256u + threadIdx.x;
    bias[i] = fmaf(beps[i], exp2f(blv[i] * HALF_LOG2E), bmu[i]);
  }
}

// ---------------------------------------------------------------------------
// Fused variational GEMM, TLP-hidden latency (4 WGs/CU):
//   WG = 16 cols x 256 rows x (K/KSPLIT); 4 waves, wave = 64 rows.
//   Per iter: STAGE(t+1) async raw fp32 W tile -> sync -> CVT (raw->bf16
//   swizzled, shared) -> sync -> COMP (a-frags from L2-resident bf16 xs).
//   KSPLIT>1 writes fp32 partials (reduced + bias by reduce_kernel).
// ---------------------------------------------------------------------------
template<int NSPLIT, bool USE_XS>
__global__ __launch_bounds__(TPB, 4)
void vgemm(const uint16_t* __restrict__ xs,
           const float*    __restrict__ xf,
           const float*    __restrict__ wmu,
           const float*    __restrict__ wlv,
           const float*    __restrict__ weps,
           const float*    __restrict__ biasp,
           const float*    __restrict__ bmu,
           const float*    __restrict__ blv,
           const float*    __restrict__ beps,
           float*          __restrict__ out)   // y (NSPLIT==1) or partials
{
  __shared__ __align__(16) uint8_t lds[LDS_TOTAL];

  const int tid = threadIdx.x;
  const int wv  = tid >> 6;
  const int l   = tid & 63;
  const int col_tile = blockIdx.x / NSPLIT;
  const int ks       = blockIdx.x % NSPLIT;
  const int n0  = col_tile * BN;
  const int k0  = ks * (IN_F / NSPLIT);
  const int NT  = (IN_F / NSPLIT) / BK;

  // --- staging: wave wv loads rows 4wv..4wv+3 of each array, linear LDS
  const size_t sgoff = (size_t)(n0 + 4 * wv + (l >> 4)) * IN_F + k0 + ((l & 15) << 2);

  // --- CVT addressing: thread -> (row r, 4-float slot i)
  const int cr = tid >> 4;
  const int ci = tid & 15;
  const int bfw = cr * 128 + ((((ci >> 1) ^ (cr & 7)) << 4)) + ((ci & 1) << 3);

  // --- fragment addressing
  const int br = l & 15;       // B row = output col offset
  const int kb = l >> 4;       // k-octet within k32
  const int bfo0 = br * 128 + ((((0 * 4 + kb)) ^ (br & 7)) << 4);
  const int bfo1 = br * 128 + ((((1 * 4 + kb)) ^ (br & 7)) << 4);
  const int arow0 = wv * 64 + br;

  f32x4 acc[4] = {{0,0,0,0},{0,0,0,0},{0,0,0,0},{0,0,0,0}};

  auto STAGE = [&](int t, int buf) {
    const size_t go = sgoff + (size_t)t * BK;
    uint8_t* base = &lds[0] + buf * RAW_BUF + wv * 1024;
    gload_lds16(wmu  + go, base + 0 * RAW_ARR);
    gload_lds16(wlv  + go, base + 1 * RAW_ARR);
    gload_lds16(weps + go, base + 2 * RAW_ARR);
  };

  auto CVT = [&](int buf) {
    const uint8_t* rb = &lds[0] + buf * RAW_BUF;
    f32x4 m = *(const f32x4*)(rb + 0 * RAW_ARR + tid * 16);
    f32x4 v = *(const f32x4*)(rb + 1 * RAW_ARR + tid * 16);
    f32x4 e = *(const f32x4*)(rb + 2 * RAW_ARR + tid * 16);
    u32x2 o;
    o[0] = pack2bf(fmaf(e[0], exp2f(v[0] * HALF_LOG2E), m[0]),
                   fmaf(e[1], exp2f(v[1] * HALF_LOG2E), m[1]));
    o[1] = pack2bf(fmaf(e[2], exp2f(v[2] * HALF_LOG2E), m[2]),
                   fmaf(e[3], exp2f(v[3] * HALF_LOG2E), m[3]));
    *(u32x2*)(&lds[0] + BF_BASE + bfw) = o;
  };

  auto COMP = [&](int t) {
    const uint8_t* bfb = &lds[0] + BF_BASE;
    bf16x8 b0 = *(const bf16x8*)(bfb + bfo0);
    bf16x8 b1 = *(const bf16x8*)(bfb + bfo1);
    const size_t kb0 = (size_t)k0 + t * BK + kb * 8;
#pragma unroll
    for (int j = 0; j < 4; ++j) {
      bf16x8 a0, a1;
      if constexpr (USE_XS) {
        const uint16_t* xp = xs + (size_t)(arow0 + 16 * j) * IN_F + kb0;
        a0 = *(const bf16x8*)(xp);
        a1 = *(const bf16x8*)(xp + 32);
      } else {
        const float* xp = xf + (size_t)(arow0 + 16 * j) * IN_F + kb0;
        a0 = cvt8(xp);
        a1 = cvt8(xp + 32);
      }
      acc[j] = MFMA(a0, b0, acc[j]);
      acc[j] = MFMA(a1, b1, acc[j]);
    }
  };

  STAGE(0, 0);
  for (int t = 0; t < NT; ++t) {
    if (t + 1 < NT) STAGE(t + 1, (t + 1) & 1);
    __syncthreads();          // raw[t&1] landed (drains in-flight stage too;
                              // 3 other WGs on this CU cover the stall)
    CVT(t & 1);
    __syncthreads();          // bf16 tile visible
    COMP(t);
  }

  // ---- epilogue: D[row=(l>>4)*4+i][col=l&15] per frag (validated R1/R2)
  const int col = n0 + br;
  if constexpr (NSPLIT == 1) {
    float bv;
    if constexpr (USE_XS) bv = biasp[col];
    else bv = fmaf(beps[col], exp2f(blv[col] * HALF_LOG2E), bmu[col]);
#pragma unroll
    for (int j = 0; j < 4; ++j) {
      const int rbase = wv * 64 + j * 16 + kb * 4;
#pragma unroll
      for (int i = 0; i < 4; ++i)
        out[(size_t)(rbase + i) * OUT_F + col] = acc[j][i] + bv;
    }
  } else {
    float* po = out + (size_t)ks * BATCH * OUT_F;
#pragma unroll
    for (int j = 0; j < 4; ++j) {
      const int rbase = wv * 64 + j * 16 + kb * 4;
#pragma unroll
      for (int i = 0; i < 4; ++i)
        po[(size_t)(rbase + i) * OUT_F + col] = acc[j][i];
    }
  }
}

// ---------------------------------------------------------------------------
// Reduce: y = sum_{ks} partial[ks] + bias ; one f32x4 per thread.
// ---------------------------------------------------------------------------
__global__ __launch_bounds__(256) void reduce_kernel(
    const float* __restrict__ parts,
    const float* __restrict__ bias,
    float* __restrict__ y)
{
  const size_t e = ((size_t)blockIdx.x * 256 + threadIdx.x) * 4;
  f32x4 s = *(const f32x4*)(parts + e);
#pragma unroll
  for (int p = 1; p < KSPLIT; ++p)
    s += *(const f32x4*)(parts + (size_t)p * BATCH * OUT_F + e);
  s += *(const f32x4*)(bias + (e & (OUT_F - 1)));
  *(f32x4*)(y + e) = s;
}

// ---------------------------------------------------------------------------
extern "C" void kernel_launch(void* const* d_in, const int* in_sizes, int n_in,
                              void* d_out, int out_size, void* d_ws, size_t ws_size,
                              hipStream_t stream) {
  const float* x    = (const float*)d_in[0];
  const float* wmu  = (const float*)d_in[1];
  const float* wlv  = (const float*)d_in[2];
  const float* bmu  = (const float*)d_in[3];
  const float* blv  = (const float*)d_in[4];
  const float* weps = (const float*)d_in[5];
  const float* beps = (const float*)d_in[6];
  float* y = (float*)d_out;

  const size_t xs_b   = (size_t)BATCH * IN_F * 2;            // 2 MiB
  const size_t bias_b = (size_t)OUT_F * 4;                   // 16 KiB
  const size_t part_b = (size_t)KSPLIT * BATCH * OUT_F * 4;  // 16 MiB

  if (d_ws != nullptr && ws_size >= xs_b + bias_b + part_b) {
    uint16_t* xsp   = (uint16_t*)d_ws;
    float*    bias  = (float*)((char*)d_ws + xs_b);
    float*    parts = (float*)((char*)d_ws + xs_b + bias_b);
    prep_kernel<<<528, 256, 0, stream>>>(x, bmu, blv, beps, (u32x4*)d_ws, bias);
    vgemm<KSPLIT, true><<<(OUT_F / BN) * KSPLIT, TPB, 0, stream>>>(
        xsp, nullptr, wmu, wlv, weps, bias, nullptr, nullptr, nullptr, parts);
    reduce_kernel<<<(BATCH * OUT_F) / (256 * 4), 256, 0, stream>>>(parts, bias, y);
  } else if (d_ws != nullptr && ws_size >= xs_b + bias_b) {
    uint16_t* xsp  = (uint16_t*)d_ws;
    float*    bias = (float*)((char*)d_ws + xs_b);
    prep_kernel<<<528, 256, 0, stream>>>(x, bmu, blv, beps, (u32x4*)d_ws, bias);
    vgemm<1, true><<<OUT_F / BN, TPB, 0, stream>>>(
        xsp, nullptr, wmu, wlv, weps, bias, nullptr, nullptr, nullptr, y);
  } else {
    vgemm<1, false><<<OUT_F / BN, TPB, 0, stream>>>(
        nullptr, x, wmu, wlv, weps, nullptr, bmu, blv, beps, y);
  }
}